// Round 5
// baseline (655.672 us; speedup 1.0000x reference)
//
#include <hip/hip_runtime.h>

// Problem constants (from reference)
#define E_TOT   50000
#define DD      256
#define TE      4               // edges per workgroup
#define NGROUP  (E_TOT / TE)    // 12500
#define SCALE_V 0.125f          // HD^-0.5

typedef __attribute__((ext_vector_type(4))) float f32x4;
typedef __attribute__((ext_vector_type(8))) short short8;

__device__ __forceinline__ unsigned short f2bf(float f) {
    unsigned u = __float_as_uint(f);
    u += 0x7fffu + ((u >> 16) & 1u);   // RNE
    return (unsigned short)(u >> 16);
}
__device__ __forceinline__ float gelu_exact(float x) {
    return 0.5f * x * (1.0f + erff(x * 0.70710678118654752440f));
}
__device__ __forceinline__ float sigmoidf(float x) {
    return 1.0f / (1.0f + __expf(-x));
}

// ---------------------------------------------------------------------------
// Kernel P: Wq/Wk (f32 [k][n]) -> bf16 [n][k]; We1 (f32 [256][128]) -> bf16
// [n][k]. B-fragments become contiguous 16B loads.
// ---------------------------------------------------------------------------
__global__ void prep_weights(const float* __restrict__ Wq,
                             const float* __restrict__ Wk,
                             const float* __restrict__ We1,
                             unsigned short* __restrict__ wqT,
                             unsigned short* __restrict__ wkT,
                             unsigned short* __restrict__ w1T) {
    int i = blockIdx.x * 256 + threadIdx.x;       // grid 640*256 = 163840
    if (i < 65536) {
        int k = i >> 8, n = i & 255;
        wqT[n * 256 + k] = f2bf(Wq[i]);
    } else if (i < 131072) {
        int j = i - 65536;
        int k = j >> 8, n = j & 255;
        wkT[n * 256 + k] = f2bf(Wk[j]);
    } else {
        int j = i - 131072;                        // 0..32767, [k][n] n<128
        int k = j >> 7, n = j & 127;
        w1T[n * 256 + k] = f2bf(We1[j]);
    }
}

// ---------------------------------------------------------------------------
// Fused kernel.
// ---------------------------------------------------------------------------
__device__ __forceinline__ void proj_gemm(const unsigned short (*A)[260],
                                          const unsigned short* __restrict__ Wt,
                                          f32x4 acc[2][4], int lr, int lq, int w) {
    #pragma unroll
    for (int ks = 0; ks < 8; ++ks) {
        short8 a0 = *(const short8*)&A[lr][ks * 32 + lq * 8];
        short8 a1 = *(const short8*)&A[16 + lr][ks * 32 + lq * 8];
        #pragma unroll
        for (int n = 0; n < 4; ++n) {
            const int col = (w * 4 + n) * 16 + lr;
            short8 bv = *(const short8*)(Wt + col * 256 + ks * 32 + lq * 8);
            acc[0][n] = __builtin_amdgcn_mfma_f32_16x16x32_bf16(a0, bv, acc[0][n], 0, 0, 0);
            acc[1][n] = __builtin_amdgcn_mfma_f32_16x16x32_bf16(a1, bv, acc[1][n], 0, 0, 0);
        }
    }
}

__device__ __forceinline__ void writeback(unsigned short (*T)[260],
                                          const f32x4 acc[2][4],
                                          const float* __restrict__ bias,
                                          int lr, int lq, int w) {
    #pragma unroll
    for (int n = 0; n < 4; ++n) {
        const int col = (w * 4 + n) * 16 + lr;
        const float bs = bias[col];
        #pragma unroll
        for (int m = 0; m < 2; ++m) {
            #pragma unroll
            for (int v = 0; v < 4; ++v) {
                const int row = m * 16 + lq * 4 + v;   // verified C/D layout
                T[row][col] = f2bf(acc[m][n][v] + bs);
            }
        }
    }
}

__global__ __launch_bounds__(256, 4)
void fused_all(const float* __restrict__ x_i,
               const float* __restrict__ x_j,
               const float* __restrict__ h_i,
               const float* __restrict__ h_j,
               const float* __restrict__ emb,
               const unsigned short* __restrict__ wqT,
               const unsigned short* __restrict__ wkT,
               const unsigned short* __restrict__ w1T,
               const float* __restrict__ bq,
               const float* __restrict__ bk,
               const float* __restrict__ be1,
               const float* __restrict__ We2,
               const float* __restrict__ be2,
               const float* __restrict__ Wo1,
               const float* __restrict__ bo1,
               const float* __restrict__ Wo2,
               const float* __restrict__ bo2,
               float* __restrict__ out) {
    // [260] pad: measured 0 bank conflicts (round 4). bufHI: h_i then Q;
    // bufHJ: h_j then K.
    __shared__ unsigned short bufHI[32][260];
    __shared__ unsigned short bufHJ[32][260];
    __shared__ float sEdgeP[4][4];     // [wave][edge] edge-MLP partials

    const int t  = threadIdx.x;
    const int w  = t >> 6;            // wave 0..3 (owns edge w, N-cols w*64..)
    const int l  = t & 63;
    const int lr = l & 15, lq = l >> 4;
    const int g  = blockIdx.x;
    const int e  = g * TE + w;
    const size_t hbase = (size_t)g * (TE * 8 * DD);

    // ---- phase L: issue everything, then convert ----
    f32x4 xa = *(const f32x4*)(x_i + (size_t)e * DD + l * 4);
    f32x4 xb = *(const f32x4*)(x_j + (size_t)e * DD + l * 4);
    f32x4 si[8], sj[8];
    #pragma unroll
    for (int i = 0; i < 8; ++i)
        si[i] = *(const f32x4*)(h_i + hbase + (size_t)(i * 256 + t) * 4);
    #pragma unroll
    for (int i = 0; i < 8; ++i)
        sj[i] = *(const f32x4*)(h_j + hbase + (size_t)(i * 256 + t) * 4);
    __builtin_amdgcn_sched_barrier(0);   // pin: all 16 issues precede stores

    #pragma unroll
    for (int i = 0; i < 8; ++i) {        // waits vmcnt(8): sj stays in flight
        const int f = i * 256 + t;
        *(ushort4*)&bufHI[f >> 6][(f & 63) * 4] =
            make_ushort4(f2bf(si[i][0]), f2bf(si[i][1]), f2bf(si[i][2]), f2bf(si[i][3]));
    }
    #pragma unroll
    for (int i = 0; i < 8; ++i) {
        const int f = i * 256 + t;
        *(ushort4*)&bufHJ[f >> 6][(f & 63) * 4] =
            make_ushort4(f2bf(sj[i][0]), f2bf(sj[i][1]), f2bf(sj[i][2]), f2bf(sj[i][3]));
    }
    // cosine partials (reduce deferred to the end)
    float cd = xa[0]*xb[0] + xa[1]*xb[1] + xa[2]*xb[2] + xa[3]*xb[3];
    float ci = xa[0]*xa[0] + xa[1]*xa[1] + xa[2]*xa[2] + xa[3]*xa[3];
    float cj = xb[0]*xb[0] + xb[1]*xb[1] + xb[2]*xb[2] + xb[3]*xb[3];
    __syncthreads();                                   // B1

    // ---- edge-MLP GEMM (emb from HBM in-loop) + epilogue -> sEdgeP ----
    {
        f32x4 accE[2] = {};
        const float* embrow = emb + ((size_t)g * TE + (lr & 3)) * DD;
        #pragma unroll
        for (int ks = 0; ks < 8; ++ks) {
            f32x4 e0 = *(const f32x4*)(embrow + ks * 32 + lq * 8);
            f32x4 e1 = *(const f32x4*)(embrow + ks * 32 + lq * 8 + 4);
            short8 ae;
            ae[0] = (short)f2bf(e0[0]); ae[1] = (short)f2bf(e0[1]);
            ae[2] = (short)f2bf(e0[2]); ae[3] = (short)f2bf(e0[3]);
            ae[4] = (short)f2bf(e1[0]); ae[5] = (short)f2bf(e1[1]);
            ae[6] = (short)f2bf(e1[2]); ae[7] = (short)f2bf(e1[3]);
            #pragma unroll
            for (int n = 0; n < 2; ++n) {
                const int col = w * 32 + n * 16 + lr;
                short8 bv = *(const short8*)(w1T + col * 256 + ks * 32 + lq * 8);
                accE[n] = __builtin_amdgcn_mfma_f32_16x16x32_bf16(ae, bv, accE[n], 0, 0, 0);
            }
        }
        float p[4] = {0.f, 0.f, 0.f, 0.f};
        #pragma unroll
        for (int n = 0; n < 2; ++n) {
            const int col = w * 32 + n * 16 + lr;
            const float b1 = be1[col], w2 = We2[col];
            #pragma unroll
            for (int v = 0; v < 4; ++v)          // C row lq*4+v ≡ edge v
                p[v] += gelu_exact(accE[n][v] + b1) * w2;
        }
        #pragma unroll
        for (int off = 1; off < 16; off <<= 1) {
            #pragma unroll
            for (int v = 0; v < 4; ++v) p[v] += __shfl_xor(p[v], off);
        }
        if (l == 0) {
            sEdgeP[w][0] = p[0]; sEdgeP[w][1] = p[1];
            sEdgeP[w][2] = p[2]; sEdgeP[w][3] = p[3];
        }
    }

    // ---- Q/K projection GEMMs (B-frags from L2) ----
    f32x4 accQ[2][4] = {};
    f32x4 accK[2][4] = {};
    proj_gemm(bufHI, wqT, accQ, lr, lq, w);
    proj_gemm(bufHJ, wkT, accK, lr, lq, w);
    __syncthreads();                                   // B2: reads done
    writeback(bufHI, accQ, bq, lr, lq, w);             // bufHI := Q
    writeback(bufHJ, accK, bk, lr, lq, w);             // bufHJ := K
    __syncthreads();                                   // B3

    // ---- scores: S^T = K·Q^T per head; lane holds S[q=lr&7][4 k-values] ----
    float contrib = 0.f;
    #pragma unroll
    for (int h = 0; h < 4; ++h) {
        f32x4 s = {};
        #pragma unroll
        for (int ks = 0; ks < 2; ++ks) {
            short8 a = *(const short8*)&bufHJ[w * 8 + (lr & 7)][h * 64 + ks * 32 + lq * 8];
            short8 b = *(const short8*)&bufHI[w * 8 + (lr & 7)][h * 64 + ks * 32 + lq * 8];
            s = __builtin_amdgcn_mfma_f32_16x16x32_bf16(a, b, s, 0, 0, 0);
        }
        // C[row=lq*4+v][col=lr]: S[q=lr&7][k=(lq*4+v)&7]
        float sc[4];
        #pragma unroll
        for (int v = 0; v < 4; ++v) sc[v] = s[v] * SCALE_V;
        float m4 = fmaxf(fmaxf(sc[0], sc[1]), fmaxf(sc[2], sc[3]));
        float mx = fmaxf(m4, __shfl_xor(m4, 16));      // combine k-halves
        float pe[4], ps = 0.f;
        #pragma unroll
        for (int v = 0; v < 4; ++v) { pe[v] = __expf(sc[v] - mx); ps += pe[v]; }
        float tot = ps + __shfl_xor(ps, 16);
        float pd = 0.f;
        #pragma unroll
        for (int v = 0; v < 4; ++v)
            pd = (((lq * 4 + v) & 7) == (lr & 7)) ? pe[v] : pd;   // diag k==q
        if (lr < 8 && lq < 2) contrib += pd / tot;     // dedup replicas
    }

    // ---- final wave reductions (scores + cosine together) ----
    #pragma unroll
    for (int off = 1; off < 64; off <<= 1) {
        contrib += __shfl_xor(contrib, off);
        cd += __shfl_xor(cd, off);
        ci += __shfl_xor(ci, off);
        cj += __shfl_xor(cj, off);
    }
    const float act  = contrib * (1.0f / 32.0f);       // mean over NH*K
    const float attr = (cd / (fmaxf(sqrtf(ci), 1e-8f) * fmaxf(sqrtf(cj), 1e-8f))
                        + 1.0f) * 0.5f;
    const float es = sigmoidf(sEdgeP[0][w] + sEdgeP[1][w] + sEdgeP[2][w] +
                              sEdgeP[3][w] + be2[0]);

    float r = 0.f;
    if (l < 16) {
        float z = attr * Wo1[l] + act * Wo1[16 + l] + es * Wo1[32 + l] + bo1[l];
        r = gelu_exact(z) * Wo2[l];
    }
    r += __shfl_xor(r, 1);
    r += __shfl_xor(r, 2);
    r += __shfl_xor(r, 4);
    r += __shfl_xor(r, 8);
    if (l == 0) out[e] = sigmoidf(r + bo2[0]);
}

// ---------------------------------------------------------------------------
extern "C" void kernel_launch(void* const* d_in, const int* in_sizes, int n_in,
                              void* d_out, int out_size, void* d_ws, size_t ws_size,
                              hipStream_t stream) {
    const float* x_i  = (const float*)d_in[0];
    const float* x_j  = (const float*)d_in[1];
    const float* h_i  = (const float*)d_in[2];
    const float* h_j  = (const float*)d_in[3];
    const float* emb  = (const float*)d_in[4];
    const float* Wq   = (const float*)d_in[5];
    const float* bq   = (const float*)d_in[6];
    const float* Wk   = (const float*)d_in[7];
    const float* bk   = (const float*)d_in[8];
    const float* We1  = (const float*)d_in[9];
    const float* be1  = (const float*)d_in[10];
    const float* We2  = (const float*)d_in[11];
    const float* be2  = (const float*)d_in[12];
    const float* Wo1  = (const float*)d_in[13];
    const float* bo1  = (const float*)d_in[14];
    const float* Wo2  = (const float*)d_in[15];
    const float* bo2  = (const float*)d_in[16];
    float* out = (float*)d_out;

    // workspace: wqT 131072B | wkT 131072B | w1T 65536B
    unsigned short* wqT = (unsigned short*)d_ws;
    unsigned short* wkT = wqT + 65536;
    unsigned short* w1T = wkT + 65536;

    prep_weights<<<640, 256, 0, stream>>>(Wq, Wk, We1, wqT, wkT, w1T);
    fused_all<<<NGROUP, 256, 0, stream>>>(x_i, x_j, h_i, h_j, emb,
                                          wqT, wkT, w1T,
                                          bq, bk, be1, We2, be2,
                                          Wo1, bo1, Wo2, bo2, out);
}

// Round 6
// 607.456 us; speedup vs baseline: 1.0794x; 1.0794x over previous
//
#include <hip/hip_runtime.h>

// Problem constants (from reference)
#define E_TOT   50000
#define DD      256
#define TE      4               // edges per workgroup
#define NGROUP  (E_TOT / TE)    // 12500
#define SCALE_V 0.125f          // HD^-0.5

typedef __attribute__((ext_vector_type(4))) float f32x4;
typedef __attribute__((ext_vector_type(8))) short short8;

__device__ __forceinline__ unsigned short f2bf(float f) {
    unsigned u = __float_as_uint(f);
    u += 0x7fffu + ((u >> 16) & 1u);   // RNE
    return (unsigned short)(u >> 16);
}
__device__ __forceinline__ float gelu_exact(float x) {
    return 0.5f * x * (1.0f + erff(x * 0.70710678118654752440f));
}
__device__ __forceinline__ float sigmoidf(float x) {
    return 1.0f / (1.0f + __expf(-x));
}

// Inline-asm global load: issue is pinned at this program point (asm volatile
// order is preserved); result regs stay live until the manual vmcnt wait.
__device__ __forceinline__ f32x4 aload(const float* p) {
    f32x4 r;
    asm volatile("global_load_dwordx4 %0, %1, off" : "=v"(r) : "v"(p));
    return r;
}
#define WAITV(N) do { asm volatile("s_waitcnt vmcnt(" #N ")" ::: "memory"); \
                      __builtin_amdgcn_sched_barrier(0); } while (0)

// ---------------------------------------------------------------------------
// Kernel P: Wq/Wk (f32 [k][n]) -> bf16 [n][k]; We1 (f32 [256][128]) -> bf16
// [n][k]. B-fragments become contiguous 16B loads.
// ---------------------------------------------------------------------------
__global__ void prep_weights(const float* __restrict__ Wq,
                             const float* __restrict__ Wk,
                             const float* __restrict__ We1,
                             unsigned short* __restrict__ wqT,
                             unsigned short* __restrict__ wkT,
                             unsigned short* __restrict__ w1T) {
    int i = blockIdx.x * 256 + threadIdx.x;       // grid 640*256 = 163840
    if (i < 65536) {
        int k = i >> 8, n = i & 255;
        wqT[n * 256 + k] = f2bf(Wq[i]);
    } else if (i < 131072) {
        int j = i - 65536;
        int k = j >> 8, n = j & 255;
        wkT[n * 256 + k] = f2bf(Wk[j]);
    } else {
        int j = i - 131072;                        // 0..32767, [k][n] n<128
        int k = j >> 7, n = j & 127;
        w1T[n * 256 + k] = f2bf(We1[j]);
    }
}

// ---------------------------------------------------------------------------
// Fused kernel.
// ---------------------------------------------------------------------------
__device__ __forceinline__ void proj_gemm(const unsigned short (*A)[260],
                                          const unsigned short* __restrict__ Wt,
                                          f32x4 acc[2][4], int lr, int lq, int w) {
    #pragma unroll
    for (int ks = 0; ks < 8; ++ks) {
        short8 a0 = *(const short8*)&A[lr][ks * 32 + lq * 8];
        short8 a1 = *(const short8*)&A[16 + lr][ks * 32 + lq * 8];
        #pragma unroll
        for (int n = 0; n < 4; ++n) {
            const int col = (w * 4 + n) * 16 + lr;
            short8 bv = *(const short8*)(Wt + col * 256 + ks * 32 + lq * 8);
            acc[0][n] = __builtin_amdgcn_mfma_f32_16x16x32_bf16(a0, bv, acc[0][n], 0, 0, 0);
            acc[1][n] = __builtin_amdgcn_mfma_f32_16x16x32_bf16(a1, bv, acc[1][n], 0, 0, 0);
        }
    }
}

__device__ __forceinline__ void writeback(unsigned short (*T)[260],
                                          const f32x4 acc[2][4],
                                          const float* __restrict__ bias,
                                          int lr, int lq, int w) {
    #pragma unroll
    for (int n = 0; n < 4; ++n) {
        const int col = (w * 4 + n) * 16 + lr;
        const float bs = bias[col];
        #pragma unroll
        for (int m = 0; m < 2; ++m) {
            #pragma unroll
            for (int v = 0; v < 4; ++v) {
                const int row = m * 16 + lq * 4 + v;   // verified C/D layout
                T[row][col] = f2bf(acc[m][n][v] + bs);
            }
        }
    }
}

__global__ __launch_bounds__(256, 3)
void fused_all(const float* __restrict__ x_i,
               const float* __restrict__ x_j,
               const float* __restrict__ h_i,
               const float* __restrict__ h_j,
               const float* __restrict__ emb,
               const unsigned short* __restrict__ wqT,
               const unsigned short* __restrict__ wkT,
               const unsigned short* __restrict__ w1T,
               const float* __restrict__ bq,
               const float* __restrict__ bk,
               const float* __restrict__ be1,
               const float* __restrict__ We2,
               const float* __restrict__ be2,
               const float* __restrict__ Wo1,
               const float* __restrict__ bo1,
               const float* __restrict__ Wo2,
               const float* __restrict__ bo2,
               float* __restrict__ out) {
    // tI: h_i then Q (bf16); tJ: h_j then K. [260] pad: 0 bank conflicts (r4/r5).
    __shared__ unsigned short tI[32][260];
    __shared__ unsigned short tJ[32][260];
    __shared__ float sEmb[TE][DD];     // emb rows, staged once
    __shared__ float sEdgeP[4][4];     // [wave][edge] edge-MLP partials

    const int t  = threadIdx.x;
    const int w  = t >> 6;            // wave 0..3 (owns edge w, N-cols w*64..)
    const int l  = t & 63;
    const int lr = l & 15, lq = l >> 4;
    const int g  = blockIdx.x;
    const int e  = g * TE + w;
    const size_t hbase = (size_t)g * (TE * 8 * DD);

    // ---- phase L: 19 asm loads, all in flight before any wait ----
    f32x4 si[8], sj[8];
    #pragma unroll
    for (int i = 0; i < 8; ++i)
        si[i] = aload(h_i + hbase + (size_t)(i * 256 + t) * 4);
    #pragma unroll
    for (int i = 0; i < 8; ++i)
        sj[i] = aload(h_j + hbase + (size_t)(i * 256 + t) * 4);
    f32x4 xa = aload(x_i + (size_t)e * DD + l * 4);
    f32x4 xb = aload(x_j + (size_t)e * DD + l * 4);
    f32x4 em = aload(emb + ((size_t)g * TE + (t >> 6)) * DD + (t & 63) * 4);
    __builtin_amdgcn_sched_barrier(0);

    WAITV(11);                         // si landed (sj + x + emb in flight)
    #pragma unroll
    for (int i = 0; i < 8; ++i) {
        const int f = i * 256 + t;
        *(ushort4*)&tI[f >> 6][(f & 63) * 4] =
            make_ushort4(f2bf(si[i][0]), f2bf(si[i][1]), f2bf(si[i][2]), f2bf(si[i][3]));
    }
    WAITV(3);                          // sj landed
    #pragma unroll
    for (int i = 0; i < 8; ++i) {
        const int f = i * 256 + t;
        *(ushort4*)&tJ[f >> 6][(f & 63) * 4] =
            make_ushort4(f2bf(sj[i][0]), f2bf(sj[i][1]), f2bf(sj[i][2]), f2bf(sj[i][3]));
    }
    WAITV(0);                          // xa, xb, em landed
    *(f32x4*)&sEmb[t >> 6][(t & 63) * 4] = em;
    float cd = xa[0]*xb[0] + xa[1]*xb[1] + xa[2]*xb[2] + xa[3]*xb[3];
    float ci = xa[0]*xa[0] + xa[1]*xa[1] + xa[2]*xa[2] + xa[3]*xa[3];
    float cj = xb[0]*xb[0] + xb[1]*xb[1] + xb[2]*xb[2] + xb[3]*xb[3];
    __syncthreads();                                   // B1

    // ---- Q-GEMM + edge-MLP GEMM (A from sEmb LDS, B from L2) ----
    f32x4 accE[2] = {};
    {
        #pragma unroll
        for (int ks = 0; ks < 8; ++ks) {
            f32x4 e0 = *(const f32x4*)&sEmb[lr & 3][ks * 32 + lq * 8];
            f32x4 e1 = *(const f32x4*)&sEmb[lr & 3][ks * 32 + lq * 8 + 4];
            short8 ae;
            ae[0] = (short)f2bf(e0[0]); ae[1] = (short)f2bf(e0[1]);
            ae[2] = (short)f2bf(e0[2]); ae[3] = (short)f2bf(e0[3]);
            ae[4] = (short)f2bf(e1[0]); ae[5] = (short)f2bf(e1[1]);
            ae[6] = (short)f2bf(e1[2]); ae[7] = (short)f2bf(e1[3]);
            #pragma unroll
            for (int n = 0; n < 2; ++n) {
                const int col = w * 32 + n * 16 + lr;
                short8 bv = *(const short8*)(w1T + col * 256 + ks * 32 + lq * 8);
                accE[n] = __builtin_amdgcn_mfma_f32_16x16x32_bf16(ae, bv, accE[n], 0, 0, 0);
            }
        }
    }
    {
        f32x4 accQ[2][4] = {};
        proj_gemm(tI, wqT, accQ, lr, lq, w);
        __syncthreads();                               // B2: tI reads done
        writeback(tI, accQ, bq, lr, lq, w);            // tI := Q
    }
    {
        f32x4 accK[2][4] = {};
        proj_gemm(tJ, wkT, accK, lr, lq, w);           // reads tJ only
        __syncthreads();                               // B3: tJ reads + Q writes
        writeback(tJ, accK, bk, lr, lq, w);            // tJ := K
    }
    // edge-MLP epilogue -> sEdgeP
    {
        float p[4] = {0.f, 0.f, 0.f, 0.f};
        #pragma unroll
        for (int n = 0; n < 2; ++n) {
            const int col = w * 32 + n * 16 + lr;
            const float b1 = be1[col], w2 = We2[col];
            #pragma unroll
            for (int v = 0; v < 4; ++v)                // C row lq*4+v ≡ edge v
                p[v] += gelu_exact(accE[n][v] + b1) * w2;
        }
        #pragma unroll
        for (int off = 1; off < 16; off <<= 1) {
            #pragma unroll
            for (int v = 0; v < 4; ++v) p[v] += __shfl_xor(p[v], off);
        }
        if (l == 0) {
            sEdgeP[w][0] = p[0]; sEdgeP[w][1] = p[1];
            sEdgeP[w][2] = p[2]; sEdgeP[w][3] = p[3];
        }
    }
    __syncthreads();                                   // B4: tiles + sEdgeP ready

    // ---- scores: S^T = K·Q^T per head; lane holds S[q=lr&7][4 k-values] ----
    float contrib = 0.f;
    #pragma unroll
    for (int h = 0; h < 4; ++h) {
        f32x4 s = {};
        #pragma unroll
        for (int ks = 0; ks < 2; ++ks) {
            short8 a = *(const short8*)&tJ[w * 8 + (lr & 7)][h * 64 + ks * 32 + lq * 8];
            short8 b = *(const short8*)&tI[w * 8 + (lr & 7)][h * 64 + ks * 32 + lq * 8];
            s = __builtin_amdgcn_mfma_f32_16x16x32_bf16(a, b, s, 0, 0, 0);
        }
        // C[row=lq*4+v][col=lr]: S[q=lr&7][k=(lq*4+v)&7]
        float sc[4];
        #pragma unroll
        for (int v = 0; v < 4; ++v) sc[v] = s[v] * SCALE_V;
        float m4 = fmaxf(fmaxf(sc[0], sc[1]), fmaxf(sc[2], sc[3]));
        float mx = fmaxf(m4, __shfl_xor(m4, 16));      // combine k-halves
        float pe[4], ps = 0.f;
        #pragma unroll
        for (int v = 0; v < 4; ++v) { pe[v] = __expf(sc[v] - mx); ps += pe[v]; }
        float tot = ps + __shfl_xor(ps, 16);
        float pd = 0.f;
        #pragma unroll
        for (int v = 0; v < 4; ++v)
            pd = (((lq * 4 + v) & 7) == (lr & 7)) ? pe[v] : pd;   // diag k==q
        if (lr < 8 && lq < 2) contrib += pd / tot;     // dedup replicas
    }

    // ---- final wave reductions (scores + cosine together) ----
    #pragma unroll
    for (int off = 1; off < 64; off <<= 1) {
        contrib += __shfl_xor(contrib, off);
        cd += __shfl_xor(cd, off);
        ci += __shfl_xor(ci, off);
        cj += __shfl_xor(cj, off);
    }
    const float act  = contrib * (1.0f / 32.0f);       // mean over NH*K
    const float attr = (cd / (fmaxf(sqrtf(ci), 1e-8f) * fmaxf(sqrtf(cj), 1e-8f))
                        + 1.0f) * 0.5f;
    const float es = sigmoidf(sEdgeP[0][w] + sEdgeP[1][w] + sEdgeP[2][w] +
                              sEdgeP[3][w] + be2[0]);

    float r = 0.f;
    if (l < 16) {
        float z = attr * Wo1[l] + act * Wo1[16 + l] + es * Wo1[32 + l] + bo1[l];
        r = gelu_exact(z) * Wo2[l];
    }
    r += __shfl_xor(r, 1);
    r += __shfl_xor(r, 2);
    r += __shfl_xor(r, 4);
    r += __shfl_xor(r, 8);
    if (l == 0) out[e] = sigmoidf(r + bo2[0]);
}

// ---------------------------------------------------------------------------
extern "C" void kernel_launch(void* const* d_in, const int* in_sizes, int n_in,
                              void* d_out, int out_size, void* d_ws, size_t ws_size,
                              hipStream_t stream) {
    const float* x_i  = (const float*)d_in[0];
    const float* x_j  = (const float*)d_in[1];
    const float* h_i  = (const float*)d_in[2];
    const float* h_j  = (const float*)d_in[3];
    const float* emb  = (const float*)d_in[4];
    const float* Wq   = (const float*)d_in[5];
    const float* bq   = (const float*)d_in[6];
    const float* Wk   = (const float*)d_in[7];
    const float* bk   = (const float*)d_in[8];
    const float* We1  = (const float*)d_in[9];
    const float* be1  = (const float*)d_in[10];
    const float* We2  = (const float*)d_in[11];
    const float* be2  = (const float*)d_in[12];
    const float* Wo1  = (const float*)d_in[13];
    const float* bo1  = (const float*)d_in[14];
    const float* Wo2  = (const float*)d_in[15];
    const float* bo2  = (const float*)d_in[16];
    float* out = (float*)d_out;

    // workspace: wqT 131072B | wkT 131072B | w1T 65536B
    unsigned short* wqT = (unsigned short*)d_ws;
    unsigned short* wkT = wqT + 65536;
    unsigned short* w1T = wkT + 65536;

    prep_weights<<<640, 256, 0, stream>>>(Wq, Wk, We1, wqT, wkT, w1T);
    fused_all<<<NGROUP, 256, 0, stream>>>(x_i, x_j, h_i, h_j, emb,
                                          wqT, wkT, w1T,
                                          bq, bk, be1, We2, be2,
                                          Wo1, bo1, Wo2, bo2, out);
}